// Round 4
// baseline (104.483 us; speedup 1.0000x reference)
//
#include <hip/hip_runtime.h>

// x (64,3,512,512) f32, mean_params (64,4) f32.
#define BB 64
#define CC 3
#define HH 512
#define WW 512
#define HW (HH * WW)           // 262144
#define CHW (CC * HH * WW)     // 786432

typedef float f2_t __attribute__((ext_vector_type(2), aligned(4)));
typedef float f4_t __attribute__((ext_vector_type(4), aligned(16)));

// Per-batch affine coefficients in PIXEL space:
//   ix = ct*w - st*h + Cx ;  iy = st*w + ct*h + Cy
// Derivation: xs=(2w+1)/512-1 -> 256*xs = w - 255.5; ix = gx*256 + 255.5.
__global__ __launch_bounds__(64) void prep_kernel(const float* __restrict__ mp,
                                                  float4* __restrict__ cf)
{
    int b = threadIdx.x;
    if (b < BB) {
        float theta = mp[b * 4 + 0];
        float scale = mp[b * 4 + 1];
        float tx    = mp[b * 4 + 2];
        float ty    = mp[b * 4 + 3];
        float s, c;
        sincosf(theta, &s, &c);
        float ct = scale * c;
        float st = scale * s;
        const float d = -255.5f;                 // value of 256*xs at w=0
        float Cx = d * (ct - st) + 256.0f * tx + 255.5f;
        float Cy = d * (st + ct) + 256.0f * ty + 255.5f;
        cf[b] = make_float4(ct, st, Cx, Cy);
    }
}

// Block = 256 thr -> 32x32 output tile. Thread = 1x4 horizontal strip.
// Wave covers 8 rows x 32 cols (lane>>3 = row, lane&7 = 4-px strip).
__global__ __launch_bounds__(256) void affine_sample_kernel(
    const float* __restrict__ x,
    const float4* __restrict__ cf,
    float* __restrict__ out)
{
    int tid  = threadIdx.x;
    int lane = tid & 63;
    int wid  = tid >> 6;
    int strip = lane & 7;
    int lrow  = lane >> 3;

    int bidx = blockIdx.x;          // 64 batches * 256 tiles
    int b    = bidx >> 8;
    int rem  = bidx & 255;          // 16x16 tiles of 32x32
    int tileH = (rem >> 4) << 5;
    int tileW = (rem & 15) << 5;

    int h  = tileH + (wid << 3) + lrow;
    int w0 = tileW + (strip << 2);

    float4 k = cf[b];               // b is blockIdx-derived -> scalar load
    float ct = k.x, st = k.y, Cx = k.z, Cy = k.w;

    float ix = ct * (float)w0 - st * (float)h + Cx;
    float iy = st * (float)w0 + ct * (float)h + Cy;

    float al[4], ar[4], f0[4], f1[4];
    int o0[4], o1[4];
#pragma unroll
    for (int p = 0; p < 4; ++p) {
        float x0f = floorf(ix), y0f = floorf(iy);
        float fx = ix - x0f,    fy = iy - y0f;
        int x0 = (int)x0f, y0 = (int)y0f;
        int y1 = y0 + 1;

        // x-side: one f2 load at clamped base; coeffs fold clamp+mask semantics
        bool xin = (x0 >= 0) & (x0 <= WW - 2);
        float wl = 1.0f - fx;
        al[p] = xin ? wl : ((x0 == -1)     ? fx : 0.0f);
        ar[p] = xin ? fx : ((x0 == WW - 1) ? wl : 0.0f);
        int base = min(max(x0, 0), WW - 2);

        bool vy0 = (y0 >= 0) & (y0 < HH);
        bool vy1 = (y1 >= 0) & (y1 < HH);
        int y0c = min(max(y0, 0), HH - 1);
        int y1c = min(max(y1, 0), HH - 1);
        f0[p] = (1.0f - fy) * (float)vy0;
        f1[p] = fy          * (float)vy1;

        o0[p] = y0c * WW + base;
        o1[p] = y1c * WW + base;

        ix += ct;                   // incremental coords: 2 VALU per px
        iy += st;
    }

    const float* xb = x   + b * CHW;
    float*       ob = out + b * CHW + h * WW + w0;

#pragma unroll
    for (int ch = 0; ch < CC; ++ch) {
        const float* pl = xb + ch * HW;
        f4_t v;
#pragma unroll
        for (int p = 0; p < 4; ++p) {
            f2_t t = *(const f2_t*)(pl + o0[p]);
            f2_t u = *(const f2_t*)(pl + o1[p]);
            v[p] = f0[p] * (al[p] * t.x + ar[p] * t.y)
                 + f1[p] * (al[p] * u.x + ar[p] * u.y);
        }
        __builtin_nontemporal_store(v, (f4_t*)(ob + ch * HW));
    }
}

extern "C" void kernel_launch(void* const* d_in, const int* in_sizes, int n_in,
                              void* d_out, int out_size, void* d_ws, size_t ws_size,
                              hipStream_t stream)
{
    const float* x  = (const float*)d_in[0];
    const float* mp = (const float*)d_in[1];
    float* out = (float*)d_out;
    float4* cf = (float4*)d_ws;     // 64 * 16 B = 1 KB scratch

    prep_kernel<<<1, 64, 0, stream>>>(mp, cf);
    dim3 block(256);
    dim3 grid(BB * 256);            // 64 batches x 16x16 tiles of 32x32
    affine_sample_kernel<<<grid, block, 0, stream>>>(x, cf, out);
}